// Round 1
// baseline (481.494 us; speedup 1.0000x reference)
//
#include <hip/hip_runtime.h>

// PolyAttention on MI355X (gfx950).
// Pipeline: cvt f32->bf16 -> 3x GEMM (x@W^T) -> RoPE reshape (Q,K) / transpose (V)
//           -> causal poly(^4) attention (flash-style, MFMA) -> output GEMM (fp32 out).
// Shapes: b=2, n=2048, d=2048, h=16, hd=128.

typedef __bf16 bf16;
typedef __bf16 bf16x8 __attribute__((ext_vector_type(8)));
typedef __bf16 bf16x4 __attribute__((ext_vector_type(4)));
typedef float f32x4 __attribute__((ext_vector_type(4)));

#define GLD(g, l)                                                   \
  __builtin_amdgcn_global_load_lds(                                 \
      (const __attribute__((address_space(1))) void*)(g),           \
      (__attribute__((address_space(3))) void*)(l), 16, 0, 0)

// ---------- f32 -> bf16 conversion, 4 elems/thread ----------
__global__ __launch_bounds__(256) void k_cvt(const float* __restrict__ in,
                                             bf16* __restrict__ out, int n4) {
  int i = blockIdx.x * 256 + threadIdx.x;
  if (i >= n4) return;
  float4 v = reinterpret_cast<const float4*>(in)[i];
  bf16x4 o = {(bf16)v.x, (bf16)v.y, (bf16)v.z, (bf16)v.w};
  reinterpret_cast<bf16x4*>(out)[i] = o;
}

// ---------- RoPE cos/sin table: (n=2048, half=64) ----------
__global__ __launch_bounds__(256) void k_rope_tab(float* __restrict__ ct,
                                                  float* __restrict__ st) {
  int i = blockIdx.x * 256 + threadIdx.x;  // 2048*64
  if (i >= 2048 * 64) return;
  int pos = i >> 6, f = i & 63;
  // theta = 10000^(-f/64) = exp2(-f * log2(10000)/64)
  float theta = exp2f(-(float)f * 0.20762050593046014f);
  float ang = (float)pos * theta;
  ct[i] = cosf(ang);
  st[i] = sinf(ang);
}

// ---------- RoPE + reshape: (b,n,h,128) -> (b,h,n,128) ----------
__global__ __launch_bounds__(256) void k_rope(const bf16* __restrict__ in,
                                              bf16* __restrict__ out,
                                              const float* __restrict__ ct,
                                              const float* __restrict__ st) {
  int idx = blockIdx.x * 256 + threadIdx.x;  // b*n*h*64 = 4194304
  int i = idx & 63;
  int hh = (idx >> 6) & 15;
  int nn = (idx >> 10) & 2047;
  int bb = idx >> 21;
  const bf16* p = in + ((((size_t)bb * 2048 + nn) * 16 + hh) << 7);
  bf16* q = out + ((((size_t)bb * 16 + hh) * 2048 + nn) << 7);
  float x1 = (float)p[i], x2 = (float)p[i + 64];
  float c = ct[nn * 64 + i], s = st[nn * 64 + i];
  q[i] = (bf16)(x1 * c - x2 * s);
  q[i + 64] = (bf16)(x1 * s + x2 * c);
}

// ---------- V transpose: (b,n,h,128) -> (b,h,128,n) ----------
__global__ __launch_bounds__(256) void k_trv(const bf16* __restrict__ in,
                                             bf16* __restrict__ out) {
  int o = blockIdx.x * 256 + threadIdx.x;  // 8388608
  int nn = o & 2047, dd = (o >> 11) & 127, hh = (o >> 18) & 15, bb = o >> 22;
  out[o] = in[((((size_t)bb * 2048 + nn) * 16 + hh) << 7) + dd];
}

// ---------- bf16 GEMM, C = A * B^T (A: MxK, B: NxK row-major) ----------
// m97 structure: 128x128 tile, BK=64, 4 waves (2x2, 64x64 each), 16x16x32 MFMA,
// global_load_lds width 16, 2 barriers per K-step.
template <typename OutT>
__global__ __launch_bounds__(256) void k_gemm_bt(const bf16* __restrict__ A,
                                                 const bf16* __restrict__ B,
                                                 OutT* __restrict__ C,
                                                 int M, int N, int K) {
  __shared__ __align__(16) bf16 As[128 * 64];
  __shared__ __align__(16) bf16 Bs[128 * 64];
  const int tid = threadIdx.x;
  const int w = tid >> 6, l = tid & 63;
  const int lr = l & 15, g = l >> 4;
  const int tm = blockIdx.y * 128, tn = blockIdx.x * 128;
  const int wr = (w >> 1) * 64, wc = (w & 1) * 64;

  f32x4 acc[4][4] = {};

  for (int kt = 0; kt < K; kt += 64) {
#pragma unroll
    for (int r = 0; r < 4; ++r) {
      int e = r * 2048 + tid * 8;  // element offset inside 128x64 tile
      int row = e >> 6, col = e & 63;
      GLD(A + (size_t)(tm + row) * K + kt + col, As + r * 2048 + w * 512);
      GLD(B + (size_t)(tn + row) * K + kt + col, Bs + r * 2048 + w * 512);
    }
    __syncthreads();
#pragma unroll
    for (int kk = 0; kk < 64; kk += 32) {
      bf16x8 a[4], b[4];
#pragma unroll
      for (int i = 0; i < 4; ++i)
        a[i] = *reinterpret_cast<const bf16x8*>(As + (wr + i * 16 + lr) * 64 + kk + g * 8);
#pragma unroll
      for (int i = 0; i < 4; ++i)
        b[i] = *reinterpret_cast<const bf16x8*>(Bs + (wc + i * 16 + lr) * 64 + kk + g * 8);
#pragma unroll
      for (int i = 0; i < 4; ++i)
#pragma unroll
        for (int j = 0; j < 4; ++j)
          acc[i][j] = __builtin_amdgcn_mfma_f32_16x16x32_bf16(a[i], b[j], acc[i][j], 0, 0, 0);
    }
    __syncthreads();
  }
  // C/D layout: col = lane&15, row = (lane>>4)*4 + reg  (HW-verified m89/m91)
#pragma unroll
  for (int i = 0; i < 4; ++i)
#pragma unroll
    for (int j = 0; j < 4; ++j)
#pragma unroll
      for (int r = 0; r < 4; ++r) {
        int row = tm + wr + i * 16 + g * 4 + r;
        int col = tn + wc + j * 16 + lr;
        C[(size_t)row * N + col] = (OutT)acc[i][j][r];
      }
}

// ---------- causal poly^4 attention ----------
// Q,K: (bh=32, n=2048, 128) bf16 ; Vt: (bh, 128, n) bf16 ; O: (b, n, h*128) bf16
// Block: 128 q-rows, 4 waves x 32 rows. Per kv tile of 128: S=QK^T (MFMA),
// mask + ^4, denom row-sum (shfl), P->LDS(bf16), O += P@V (MFMA). Divide at end.
__global__ __launch_bounds__(256) void k_attn(const bf16* __restrict__ Q,
                                              const bf16* __restrict__ K,
                                              const bf16* __restrict__ Vt,
                                              bf16* __restrict__ O) {
  __shared__ __align__(16) bf16 Ks[128 * 128];
  __shared__ __align__(16) bf16 Vs[128 * 128];  // [hd][kv]
  __shared__ __align__(16) bf16 Ps[128 * 128];
  const int tid = threadIdx.x, w = tid >> 6, l = tid & 63;
  const int lr = l & 15, g = l >> 4;
  const int qi = blockIdx.x, bh = blockIdx.y;
  const int qbase = qi * 128;
  const size_t base = (size_t)bh * 2048 * 128;

  // hoist Q fragments (rows w*32..w*32+31) into registers
  bf16x8 qf[2][4];
#pragma unroll
  for (int mi = 0; mi < 2; ++mi)
#pragma unroll
    for (int kc = 0; kc < 4; ++kc)
      qf[mi][kc] = *reinterpret_cast<const bf16x8*>(
          Q + base + (size_t)(qbase + w * 32 + mi * 16 + lr) * 128 + kc * 32 + g * 8);

  f32x4 on[2][8] = {};   // output numerator
  float dn[2][4] = {};   // denominator per (mi, reg)

  for (int t = 0; t <= qi; ++t) {
    const bf16* kg = K + base + (size_t)t * 128 * 128;   // contiguous 128x128
    const bf16* vg = Vt + base + (size_t)t * 128;        // row stride 2048
#pragma unroll
    for (int r = 0; r < 8; ++r) {
      int e = r * 2048 + tid * 8;
      GLD(kg + e, Ks + r * 2048 + w * 512);
      int hr = e >> 7, cw = e & 127;
      GLD(vg + (size_t)hr * 2048 + cw, Vs + r * 2048 + w * 512);
    }
    __syncthreads();

    // S = Q K^T (rows w*32..+32, cols t*128..+128)
    f32x4 s[2][8] = {};
#pragma unroll
    for (int kc = 0; kc < 4; ++kc) {
      bf16x8 kb[8];
#pragma unroll
      for (int ni = 0; ni < 8; ++ni)
        kb[ni] = *reinterpret_cast<const bf16x8*>(Ks + (ni * 16 + lr) * 128 + kc * 32 + g * 8);
#pragma unroll
      for (int mi = 0; mi < 2; ++mi)
#pragma unroll
        for (int ni = 0; ni < 8; ++ni)
          s[mi][ni] = __builtin_amdgcn_mfma_f32_16x16x32_bf16(qf[mi][kc], kb[ni], s[mi][ni], 0, 0, 0);
    }

    // mask + ^4; partial row sums; write P (bf16) to LDS (own-wave rows only)
    float part[2][4] = {};
#pragma unroll
    for (int mi = 0; mi < 2; ++mi)
#pragma unroll
      for (int ni = 0; ni < 8; ++ni)
#pragma unroll
        for (int r = 0; r < 4; ++r) {
          int row = w * 32 + mi * 16 + g * 4 + r;     // local q row
          int col = t * 128 + ni * 16 + lr;           // global kv col
          float v = s[mi][ni][r];
          v = (col <= qbase + row) ? v : 0.f;
          float v2 = v * v, v4 = v2 * v2;
          part[mi][r] += v4;
          Ps[row * 128 + ni * 16 + lr] = (bf16)v4;
        }
    // reduce across the 16 lanes holding one row's columns
#pragma unroll
    for (int m = 1; m < 16; m <<= 1)
#pragma unroll
      for (int mi = 0; mi < 2; ++mi)
#pragma unroll
        for (int r = 0; r < 4; ++r)
          part[mi][r] += __shfl_xor(part[mi][r], m, 64);
#pragma unroll
    for (int mi = 0; mi < 2; ++mi)
#pragma unroll
      for (int r = 0; r < 4; ++r) dn[mi][r] += part[mi][r];

    // PV: A = own-wave P rows (same-wave LDS RAW is in-order), B = Vs [hd][kv]
#pragma unroll
    for (int kc = 0; kc < 4; ++kc) {
      bf16x8 pa[2], vb[8];
#pragma unroll
      for (int mi = 0; mi < 2; ++mi)
        pa[mi] = *reinterpret_cast<const bf16x8*>(Ps + (w * 32 + mi * 16 + lr) * 128 + kc * 32 + g * 8);
#pragma unroll
      for (int ni = 0; ni < 8; ++ni)
        vb[ni] = *reinterpret_cast<const bf16x8*>(Vs + (ni * 16 + lr) * 128 + kc * 32 + g * 8);
#pragma unroll
      for (int mi = 0; mi < 2; ++mi)
#pragma unroll
        for (int ni = 0; ni < 8; ++ni)
          on[mi][ni] = __builtin_amdgcn_mfma_f32_16x16x32_bf16(pa[mi], vb[ni], on[mi][ni], 0, 0, 0);
    }
    __syncthreads();
  }

  // epilogue: O = numerator / max(denom, eps), write (b, n, h*128)
  const int b_ = bh >> 4, h_ = bh & 15;
#pragma unroll
  for (int mi = 0; mi < 2; ++mi)
#pragma unroll
    for (int r = 0; r < 4; ++r) {
      float d = fmaxf(dn[mi][r], 1e-6f);
      float inv = 1.0f / d;
      int row = qbase + w * 32 + mi * 16 + g * 4 + r;
#pragma unroll
      for (int ni = 0; ni < 8; ++ni) {
        int col = h_ * 128 + ni * 16 + lr;
        O[((size_t)b_ * 2048 + row) * 2048 + col] = (bf16)(on[mi][ni][r] * inv);
      }
    }
}

extern "C" void kernel_launch(void* const* d_in, const int* in_sizes, int n_in,
                              void* d_out, int out_size, void* d_ws, size_t ws_size,
                              hipStream_t stream) {
  const float* x  = (const float*)d_in[0];
  const float* Wq = (const float*)d_in[1];
  const float* Wk = (const float*)d_in[2];
  const float* Wv = (const float*)d_in[3];
  const float* Wo = (const float*)d_in[4];
  float* out = (float*)d_out;

  char* p = (char*)d_ws;
  bf16* xb  = (bf16*)p; p += (size_t)8388608 * 2;   // x in bf16 (4096x2048)
  bf16* wqb = (bf16*)p; p += (size_t)4194304 * 2;
  bf16* wkb = (bf16*)p; p += (size_t)4194304 * 2;
  bf16* wvb = (bf16*)p; p += (size_t)4194304 * 2;
  bf16* wob = (bf16*)p; p += (size_t)4194304 * 2;
  bf16* tmp = (bf16*)p; p += (size_t)8388608 * 2;   // GEMM out staging (b,n,h,hd)
  bf16* Qp  = (bf16*)p; p += (size_t)8388608 * 2;   // (b,h,n,128)
  bf16* Kp  = (bf16*)p; p += (size_t)8388608 * 2;   // (b,h,n,128)
  bf16* Vt  = (bf16*)p; p += (size_t)8388608 * 2;   // (b,h,128,n)
  bf16* Ob  = (bf16*)p; p += (size_t)8388608 * 2;   // attn out (b,n,h*128)
  float* ct = (float*)p; p += (size_t)131072 * 4;
  float* st = (float*)p; p += (size_t)131072 * 4;

  k_cvt<<<8192, 256, 0, stream>>>(x, xb, 2097152);
  k_cvt<<<4096, 256, 0, stream>>>(Wq, wqb, 1048576);
  k_cvt<<<4096, 256, 0, stream>>>(Wk, wkb, 1048576);
  k_cvt<<<4096, 256, 0, stream>>>(Wv, wvb, 1048576);
  k_cvt<<<4096, 256, 0, stream>>>(Wo, wob, 1048576);
  k_rope_tab<<<512, 256, 0, stream>>>(ct, st);

  dim3 gg(16, 32);  // (N/128, M/128)
  k_gemm_bt<bf16><<<gg, 256, 0, stream>>>(xb, wqb, tmp, 4096, 2048, 2048);
  k_rope<<<16384, 256, 0, stream>>>(tmp, Qp, ct, st);
  k_gemm_bt<bf16><<<gg, 256, 0, stream>>>(xb, wkb, tmp, 4096, 2048, 2048);
  k_rope<<<16384, 256, 0, stream>>>(tmp, Kp, ct, st);
  k_gemm_bt<bf16><<<gg, 256, 0, stream>>>(xb, wvb, tmp, 4096, 2048, 2048);
  k_trv<<<32768, 256, 0, stream>>>(tmp, Vt);

  dim3 ga(16, 32);  // (q tiles, b*h)
  k_attn<<<ga, 256, 0, stream>>>(Qp, Kp, Vt, Ob);

  k_gemm_bt<float><<<gg, 256, 0, stream>>>(Ob, wob, out, 4096, 2048, 2048);
}

// Round 2
// 331.705 us; speedup vs baseline: 1.4516x; 1.4516x over previous
//
#include <hip/hip_runtime.h>

// PolyAttention on MI355X (gfx950).
// cvt f32->bf16 -> 3x GEMM (x@W^T, V writes transposed) -> RoPE (Q,K)
// -> causal poly(^4) attention (flash-style, MFMA, swizzled LDS, balanced pairs)
// -> output GEMM (fp32 out).  Shapes: b=2, n=2048, d=2048, h=16, hd=128.

typedef __bf16 bf16;
typedef __bf16 bf16x8 __attribute__((ext_vector_type(8)));
typedef __bf16 bf16x4 __attribute__((ext_vector_type(4)));
typedef float f32x4 __attribute__((ext_vector_type(4)));

#define GLD(g, l)                                                   \
  __builtin_amdgcn_global_load_lds(                                 \
      (const __attribute__((address_space(1))) void*)(g),           \
      (__attribute__((address_space(3))) void*)(l), 16, 0, 0)

#define MFMA(a, b, c) __builtin_amdgcn_mfma_f32_16x16x32_bf16(a, b, c, 0, 0, 0)

// ---------- f32 -> bf16 conversion, 4 elems/thread ----------
__global__ __launch_bounds__(256) void k_cvt(const float* __restrict__ in,
                                             bf16* __restrict__ out, int n4) {
  int i = blockIdx.x * 256 + threadIdx.x;
  if (i >= n4) return;
  float4 v = reinterpret_cast<const float4*>(in)[i];
  bf16x4 o = {(bf16)v.x, (bf16)v.y, (bf16)v.z, (bf16)v.w};
  reinterpret_cast<bf16x4*>(out)[i] = o;
}

// ---------- RoPE cos/sin table: (n=2048, half=64) ----------
__global__ __launch_bounds__(256) void k_rope_tab(float* __restrict__ ct,
                                                  float* __restrict__ st) {
  int i = blockIdx.x * 256 + threadIdx.x;
  if (i >= 2048 * 64) return;
  int pos = i >> 6, f = i & 63;
  float theta = exp2f(-(float)f * 0.20762050593046014f);  // 10000^(-f/64)
  float ang = (float)pos * theta;
  ct[i] = cosf(ang);
  st[i] = sinf(ang);
}

// ---------- RoPE + reshape: (b,n,h,128) -> (b,h,n,128) ----------
__global__ __launch_bounds__(256) void k_rope(const bf16* __restrict__ in,
                                              bf16* __restrict__ out,
                                              const float* __restrict__ ct,
                                              const float* __restrict__ st) {
  int idx = blockIdx.x * 256 + threadIdx.x;  // b*n*h*64
  int i = idx & 63;
  int hh = (idx >> 6) & 15;
  int nn = (idx >> 10) & 2047;
  int bb = idx >> 21;
  const bf16* p = in + ((((size_t)bb * 2048 + nn) * 16 + hh) << 7);
  bf16* q = out + ((((size_t)bb * 16 + hh) * 2048 + nn) << 7);
  float x1 = (float)p[i], x2 = (float)p[i + 64];
  float c = ct[nn * 64 + i], s = st[nn * 64 + i];
  q[i] = (bf16)(x1 * c - x2 * s);
  q[i + 64] = (bf16)(x1 * s + x2 * c);
}

// ---------- bf16 GEMM, C = A * B^T (m97 structure: 128x128, BK=64, 4 waves) ----------
template <typename OutT>
__global__ __launch_bounds__(256) void k_gemm_bt(const bf16* __restrict__ A,
                                                 const bf16* __restrict__ B,
                                                 OutT* __restrict__ C,
                                                 int M, int N, int K) {
  __shared__ __align__(16) bf16 As[128 * 64];
  __shared__ __align__(16) bf16 Bs[128 * 64];
  const int tid = threadIdx.x;
  const int w = tid >> 6, l = tid & 63;
  const int lr = l & 15, g = l >> 4;
  const int tm = blockIdx.y * 128, tn = blockIdx.x * 128;
  const int wr = (w >> 1) * 64, wc = (w & 1) * 64;

  f32x4 acc[4][4] = {};

  for (int kt = 0; kt < K; kt += 64) {
#pragma unroll
    for (int r = 0; r < 4; ++r) {
      int e = r * 2048 + tid * 8;
      int row = e >> 6, col = e & 63;
      GLD(A + (size_t)(tm + row) * K + kt + col, As + r * 2048 + w * 512);
      GLD(B + (size_t)(tn + row) * K + kt + col, Bs + r * 2048 + w * 512);
    }
    __syncthreads();
#pragma unroll
    for (int kk = 0; kk < 64; kk += 32) {
      bf16x8 a[4], b[4];
#pragma unroll
      for (int i = 0; i < 4; ++i)
        a[i] = *reinterpret_cast<const bf16x8*>(As + (wr + i * 16 + lr) * 64 + kk + g * 8);
#pragma unroll
      for (int i = 0; i < 4; ++i)
        b[i] = *reinterpret_cast<const bf16x8*>(Bs + (wc + i * 16 + lr) * 64 + kk + g * 8);
#pragma unroll
      for (int i = 0; i < 4; ++i)
#pragma unroll
        for (int j = 0; j < 4; ++j)
          acc[i][j] = MFMA(a[i], b[j], acc[i][j]);
    }
    __syncthreads();
  }
#pragma unroll
  for (int i = 0; i < 4; ++i)
#pragma unroll
    for (int j = 0; j < 4; ++j)
#pragma unroll
      for (int r = 0; r < 4; ++r) {
        int row = tm + wr + i * 16 + g * 4 + r;
        int col = tn + wc + j * 16 + lr;
        C[(size_t)row * N + col] = (OutT)acc[i][j][r];
      }
}

// ---------- V GEMM with transposed epilogue: writes (b,h,128,n) ----------
__global__ __launch_bounds__(256) void k_gemm_btv(const bf16* __restrict__ A,
                                                  const bf16* __restrict__ B,
                                                  bf16* __restrict__ Vt,
                                                  int M, int N, int K) {
  __shared__ __align__(16) bf16 As[128 * 64];
  __shared__ __align__(16) bf16 Bs[128 * 64];
  const int tid = threadIdx.x;
  const int w = tid >> 6, l = tid & 63;
  const int lr = l & 15, g = l >> 4;
  const int tm = blockIdx.y * 128, tn = blockIdx.x * 128;
  const int wr = (w >> 1) * 64, wc = (w & 1) * 64;

  f32x4 acc[4][4] = {};

  for (int kt = 0; kt < K; kt += 64) {
#pragma unroll
    for (int r = 0; r < 4; ++r) {
      int e = r * 2048 + tid * 8;
      int row = e >> 6, col = e & 63;
      GLD(A + (size_t)(tm + row) * K + kt + col, As + r * 2048 + w * 512);
      GLD(B + (size_t)(tn + row) * K + kt + col, Bs + r * 2048 + w * 512);
    }
    __syncthreads();
#pragma unroll
    for (int kk = 0; kk < 64; kk += 32) {
      bf16x8 a[4], b[4];
#pragma unroll
      for (int i = 0; i < 4; ++i)
        a[i] = *reinterpret_cast<const bf16x8*>(As + (wr + i * 16 + lr) * 64 + kk + g * 8);
#pragma unroll
      for (int i = 0; i < 4; ++i)
        b[i] = *reinterpret_cast<const bf16x8*>(Bs + (wc + i * 16 + lr) * 64 + kk + g * 8);
#pragma unroll
      for (int i = 0; i < 4; ++i)
#pragma unroll
        for (int j = 0; j < 4; ++j)
          acc[i][j] = MFMA(a[i], b[j], acc[i][j]);
    }
    __syncthreads();
  }
  // transposed store: token rows r=0..3 are consecutive n -> one bf16x4 store
#pragma unroll
  for (int i = 0; i < 4; ++i)
#pragma unroll
    for (int j = 0; j < 4; ++j) {
      int row0 = tm + wr + i * 16 + g * 4;  // token (4 consecutive)
      int col = tn + wc + j * 16 + lr;      // d = h*128+dd
      int bb = row0 >> 11, nn = row0 & 2047;
      int hh = col >> 7, dd = col & 127;
      bf16x4 o = {(bf16)acc[i][j][0], (bf16)acc[i][j][1],
                  (bf16)acc[i][j][2], (bf16)acc[i][j][3]};
      *reinterpret_cast<bf16x4*>(
          Vt + (((size_t)bb * 16 + hh) * 128 + dd) * 2048 + nn) = o;
    }
}

// ---------- causal poly^4 attention ----------
// Q,K: (bh=32, 2048, 128) bf16 ; Vt: (bh, 128, 2048) bf16 ; O: (b, n, h*128) bf16
// QBLK=64 (4 waves x 16 rows), KVBLK=128, balanced pairs {p, 31-p} (17 units each).
// LDS 80KB -> 2 blocks/CU. XOR-swizzled Ks/Vs (pre-swizzled GLD source) and Ps.
__global__ __launch_bounds__(256) void k_attn(const bf16* __restrict__ Q,
                                              const bf16* __restrict__ K,
                                              const bf16* __restrict__ Vt,
                                              bf16* __restrict__ O) {
  __shared__ __align__(16) bf16 Ks[128 * 128];
  __shared__ __align__(16) bf16 Vs[128 * 128];  // [hd][kv]
  __shared__ __align__(16) bf16 Ps[64 * 128];
  const int tid = threadIdx.x, w = tid >> 6, l = tid & 63;
  const int lr = l & 15, g = l >> 4;
  const int pair = blockIdx.x, bh = blockIdx.y;
  const size_t base = (size_t)bh * 2048 * 128;
  const int b_ = bh >> 4, h_ = bh & 15;

  for (int seg = 0; seg < 2; ++seg) {
    const int qt = seg ? (31 - pair) : pair;
    const int qbase = qt * 64;
    // hoist Q fragments: wave w owns rows qbase + w*16 .. +15
    bf16x8 qf[4];
#pragma unroll
    for (int kc = 0; kc < 4; ++kc)
      qf[kc] = *reinterpret_cast<const bf16x8*>(
          Q + base + (size_t)(qbase + w * 16 + lr) * 128 + kc * 32 + g * 8);

    f32x4 on[8] = {};
    float dn[4] = {};
    const int nt = (qbase >> 7) + 1;

    for (int t = 0; t < nt; ++t) {
      const bf16* kg = K + base + (size_t)t * 128 * 128;
      const bf16* vg = Vt + base + t * 128;
#pragma unroll
      for (int r = 0; r < 8; ++r) {
        int e = r * 2048 + w * 512 + l * 8;
        int row = e >> 7, c = (e >> 3) & 15;
        int sc = ((c ^ (row & 7)) << 3);  // pre-swizzled source chunk
        GLD(kg + (row << 7) + sc, Ks + r * 2048 + w * 512);
        GLD(vg + (size_t)row * 2048 + sc, Vs + r * 2048 + w * 512);
      }
      __syncthreads();

      // S = Q K^T  (16 q-rows x 128 kv-cols per wave)
      f32x4 s[8] = {};
#pragma unroll
      for (int kc = 0; kc < 4; ++kc)
#pragma unroll
        for (int ni = 0; ni < 8; ++ni) {
          bf16x8 kb = *reinterpret_cast<const bf16x8*>(
              Ks + ((ni * 16 + lr) << 7) + (((kc * 4 + g) ^ (lr & 7)) << 3));
          s[ni] = MFMA(qf[kc], kb, s[ni]);
        }

      // mask + ^4, partial row sums, swizzled Ps writes (own-wave rows)
      float part[4] = {};
#pragma unroll
      for (int ni = 0; ni < 8; ++ni)
#pragma unroll
        for (int r = 0; r < 4; ++r) {
          int lrow = g * 4 + r;
          int qrow = qbase + w * 16 + lrow;
          int col = t * 128 + ni * 16 + lr;
          float v = s[ni][r];
          v = (col <= qrow) ? v : 0.f;
          float v2 = v * v, v4 = v2 * v2;
          part[r] += v4;
          int chunk = ni * 2 + (lr >> 3);
          Ps[((w * 16 + lrow) << 7) + ((chunk ^ (lrow & 7)) << 3) + (lr & 7)] =
              (bf16)v4;
        }
#pragma unroll
      for (int m = 1; m < 16; m <<= 1)
#pragma unroll
        for (int r = 0; r < 4; ++r) part[r] += __shfl_xor(part[r], m, 64);
#pragma unroll
      for (int r = 0; r < 4; ++r) dn[r] += part[r];

      // O += P @ V  (A = own-wave P rows, B = Vs [hd][kv], both swizzled)
#pragma unroll
      for (int kc = 0; kc < 4; ++kc) {
        bf16x8 pa = *reinterpret_cast<const bf16x8*>(
            Ps + ((w * 16 + lr) << 7) + (((kc * 4 + g) ^ (lr & 7)) << 3));
#pragma unroll
        for (int ni = 0; ni < 8; ++ni) {
          bf16x8 vb = *reinterpret_cast<const bf16x8*>(
              Vs + ((ni * 16 + lr) << 7) + (((kc * 4 + g) ^ (lr & 7)) << 3));
          on[ni] = MFMA(pa, vb, on[ni]);
        }
      }
      __syncthreads();
    }

    // epilogue: O = numerator / max(denom, eps) -> (b, n, h*128)
#pragma unroll
    for (int r = 0; r < 4; ++r) {
      float inv = 1.0f / fmaxf(dn[r], 1e-6f);
      int row = qbase + w * 16 + g * 4 + r;
#pragma unroll
      for (int ni = 0; ni < 8; ++ni)
        O[((size_t)b_ * 2048 + row) * 2048 + h_ * 128 + ni * 16 + lr] =
            (bf16)(on[ni][r] * inv);
    }
  }
}

extern "C" void kernel_launch(void* const* d_in, const int* in_sizes, int n_in,
                              void* d_out, int out_size, void* d_ws, size_t ws_size,
                              hipStream_t stream) {
  const float* x  = (const float*)d_in[0];
  const float* Wq = (const float*)d_in[1];
  const float* Wk = (const float*)d_in[2];
  const float* Wv = (const float*)d_in[3];
  const float* Wo = (const float*)d_in[4];
  float* out = (float*)d_out;

  char* p = (char*)d_ws;
  bf16* xb  = (bf16*)p; p += (size_t)8388608 * 2;
  bf16* wqb = (bf16*)p; p += (size_t)4194304 * 2;
  bf16* wkb = (bf16*)p; p += (size_t)4194304 * 2;
  bf16* wvb = (bf16*)p; p += (size_t)4194304 * 2;
  bf16* wob = (bf16*)p; p += (size_t)4194304 * 2;
  bf16* tmp = (bf16*)p; p += (size_t)8388608 * 2;
  bf16* Qp  = (bf16*)p; p += (size_t)8388608 * 2;
  bf16* Kp  = (bf16*)p; p += (size_t)8388608 * 2;
  bf16* Vt  = (bf16*)p; p += (size_t)8388608 * 2;
  bf16* Ob  = (bf16*)p; p += (size_t)8388608 * 2;
  float* ct = (float*)p; p += (size_t)131072 * 4;
  float* st = (float*)p; p += (size_t)131072 * 4;

  k_cvt<<<8192, 256, 0, stream>>>(x, xb, 2097152);
  k_cvt<<<4096, 256, 0, stream>>>(Wq, wqb, 1048576);
  k_cvt<<<4096, 256, 0, stream>>>(Wk, wkb, 1048576);
  k_cvt<<<4096, 256, 0, stream>>>(Wv, wvb, 1048576);
  k_cvt<<<4096, 256, 0, stream>>>(Wo, wob, 1048576);
  k_rope_tab<<<512, 256, 0, stream>>>(ct, st);

  dim3 gg(16, 32);  // (N/128, M/128)
  k_gemm_bt<bf16><<<gg, 256, 0, stream>>>(xb, wqb, tmp, 4096, 2048, 2048);
  k_rope<<<16384, 256, 0, stream>>>(tmp, Qp, ct, st);
  k_gemm_bt<bf16><<<gg, 256, 0, stream>>>(xb, wkb, tmp, 4096, 2048, 2048);
  k_rope<<<16384, 256, 0, stream>>>(tmp, Kp, ct, st);
  k_gemm_btv<<<gg, 256, 0, stream>>>(xb, wvb, Vt, 4096, 2048, 2048);

  dim3 ga(16, 32);  // (pairs, b*h)
  k_attn<<<ga, 256, 0, stream>>>(Qp, Kp, Vt, Ob);

  k_gemm_bt<float><<<gg, 256, 0, stream>>>(Ob, wob, out, 4096, 2048, 2048);
}

// Round 3
// 298.068 us; speedup vs baseline: 1.6154x; 1.1128x over previous
//
#include <hip/hip_runtime.h>

// PolyAttention on MI355X (gfx950).
// cvt f32->bf16 -> fused QKV GEMM (256x128 tile, dbuf, swizzled LDS, V transposed)
// -> RoPE (Q,K) -> causal poly(^4) attention (XCD-local grid) -> output GEMM.
// Shapes: b=2, n=2048, d=2048, h=16, hd=128.

typedef __bf16 bf16;
typedef __bf16 bf16x8 __attribute__((ext_vector_type(8)));
typedef __bf16 bf16x4 __attribute__((ext_vector_type(4)));
typedef float f32x4 __attribute__((ext_vector_type(4)));

#define GLD(g, l)                                                   \
  __builtin_amdgcn_global_load_lds(                                 \
      (const __attribute__((address_space(1))) void*)(g),           \
      (__attribute__((address_space(3))) void*)(l), 16, 0, 0)

#define MFMA(a, b, c) __builtin_amdgcn_mfma_f32_16x16x32_bf16(a, b, c, 0, 0, 0)

// ---------- f32 -> bf16 conversion, 4 elems/thread ----------
__global__ __launch_bounds__(256) void k_cvt(const float* __restrict__ in,
                                             bf16* __restrict__ out, int n4) {
  int i = blockIdx.x * 256 + threadIdx.x;
  if (i >= n4) return;
  float4 v = reinterpret_cast<const float4*>(in)[i];
  bf16x4 o = {(bf16)v.x, (bf16)v.y, (bf16)v.z, (bf16)v.w};
  reinterpret_cast<bf16x4*>(out)[i] = o;
}

// ---------- 3x weight cvt into concatenated wqkv (6144 x 2048) ----------
__global__ __launch_bounds__(256) void k_cvt3(const float* __restrict__ a,
                                              const float* __restrict__ b,
                                              const float* __restrict__ c,
                                              bf16* __restrict__ out) {
  int i = blockIdx.x * 256 + threadIdx.x;  // < 3 * 1048576 float4-groups
  const float* src = (i < 1048576) ? a : ((i < 2097152) ? b : c);
  int off = i & 1048575;
  float4 v = reinterpret_cast<const float4*>(src)[off];
  bf16x4 o = {(bf16)v.x, (bf16)v.y, (bf16)v.z, (bf16)v.w};
  reinterpret_cast<bf16x4*>(out)[i] = o;
}

// ---------- RoPE cos/sin table: (n=2048, half=64) ----------
__global__ __launch_bounds__(256) void k_rope_tab(float* __restrict__ ct,
                                                  float* __restrict__ st) {
  int i = blockIdx.x * 256 + threadIdx.x;
  if (i >= 2048 * 64) return;
  int pos = i >> 6, f = i & 63;
  float theta = exp2f(-(float)f * 0.20762050593046014f);  // 10000^(-f/64)
  float ang = (float)pos * theta;
  ct[i] = cosf(ang);
  st[i] = sinf(ang);
}

// ---------- RoPE + reshape: (b,n,h,128) -> (b,h,n,128) ----------
__global__ __launch_bounds__(256) void k_rope(const bf16* __restrict__ in,
                                              bf16* __restrict__ out,
                                              const float* __restrict__ ct,
                                              const float* __restrict__ st) {
  int idx = blockIdx.x * 256 + threadIdx.x;  // b*n*h*64
  int i = idx & 63;
  int hh = (idx >> 6) & 15;
  int nn = (idx >> 10) & 2047;
  int bb = idx >> 21;
  const bf16* p = in + ((((size_t)bb * 2048 + nn) * 16 + hh) << 7);
  bf16* q = out + ((((size_t)bb * 16 + hh) * 2048 + nn) << 7);
  float x1 = (float)p[i], x2 = (float)p[i + 64];
  float c = ct[nn * 64 + i], s = st[nn * 64 + i];
  q[i] = (bf16)(x1 * c - x2 * s);
  q[i + 64] = (bf16)(x1 * s + x2 * c);
}

// ---------- fused QKV GEMM: C = A * B^T, A 4096x2048, B(wqkv) 6144x2048 ----------
// BM=256, BN=128, BK=64. 8 waves (4M x 2N), per-wave 64x64 (4x4 frags).
// Double-buffered swizzled LDS (96KB), burst prefetch, ONE barrier per K-tile,
// own-wave vmcnt(0) before the barrier (loads get a full tile to land).
// Epilogue: cols 0-2047 -> Qt, 2048-4095 -> Kt, 4096-6143 -> Vt transposed.
__global__ __launch_bounds__(512, 2) void k_gemm_qkv(const bf16* __restrict__ Am,
                                                     const bf16* __restrict__ Bm,
                                                     bf16* __restrict__ Qt,
                                                     bf16* __restrict__ Kt,
                                                     bf16* __restrict__ Vt) {
  __shared__ __align__(16) bf16 Sa[2][256 * 64];
  __shared__ __align__(16) bf16 Sb[2][128 * 64];
  const int tid = threadIdx.x, w = tid >> 6, l = tid & 63;
  const int lr = l & 15, g = l >> 4;
  const int wr = w >> 1, wc = w & 1;  // wave grid 4M x 2N
  const int tm = blockIdx.y * 256, tn = blockIdx.x * 128;

  // staging: per-lane pre-swizzled global source (row&7 == l>>3 for 8-row bands)
  const int sx = ((l & 7) ^ (l >> 3)) << 3;  // swizzled k-offset (elements)
  const int sra = w * 32 + (l >> 3);         // A band row (+ i*8)
  const int srb = w * 16 + (l >> 3);         // B band row (+ i*8)

  // ds_read bases (elements); chunk swizzle: ((kst*4+g) ^ (lr&7)) * 8
  const int x0 = ((0 + g) ^ (lr & 7)) << 3;
  const int x1 = ((4 + g) ^ (lr & 7)) << 3;
  const int arow = (wr * 64 + lr) * 64;
  const int brow = (wc * 64 + lr) * 64;

  f32x4 acc[4][4] = {};

#define STAGE_QKV(buf, kt)                                                     \
  {                                                                            \
    _Pragma("unroll") for (int i = 0; i < 4; ++i)                              \
        GLD(Am + (size_t)(tm + sra + i * 8) * 2048 + (kt) + sx,                \
            Sa[buf] + w * 2048 + i * 512);                                     \
    _Pragma("unroll") for (int i = 0; i < 2; ++i)                              \
        GLD(Bm + (size_t)(tn + srb + i * 8) * 2048 + (kt) + sx,                \
            Sb[buf] + w * 1024 + i * 512);                                     \
  }

  STAGE_QKV(0, 0);
  int c = 0;
  for (int t = 0; t < 32; ++t) {
    asm volatile("s_waitcnt vmcnt(0)" ::: "memory");  // own staged data landed
    __builtin_amdgcn_s_barrier();                     // everyone's landed
    asm volatile("" ::: "memory");
    const bf16* pa = Sa[c];
    const bf16* pb = Sb[c];
    bf16x8 a[4], b[4];
    // kstep 0
#pragma unroll
    for (int fm = 0; fm < 4; ++fm)
      a[fm] = *reinterpret_cast<const bf16x8*>(pa + arow + fm * 1024 + x0);
#pragma unroll
    for (int nf = 0; nf < 4; ++nf)
      b[nf] = *reinterpret_cast<const bf16x8*>(pb + brow + nf * 1024 + x0);
    if (t < 31) STAGE_QKV(c ^ 1, (t + 1) * 64);
    __builtin_amdgcn_s_setprio(1);
#pragma unroll
    for (int fm = 0; fm < 4; ++fm)
#pragma unroll
      for (int nf = 0; nf < 4; ++nf)
        acc[fm][nf] = MFMA(a[fm], b[nf], acc[fm][nf]);
    __builtin_amdgcn_s_setprio(0);
    // kstep 1
#pragma unroll
    for (int fm = 0; fm < 4; ++fm)
      a[fm] = *reinterpret_cast<const bf16x8*>(pa + arow + fm * 1024 + x1);
#pragma unroll
    for (int nf = 0; nf < 4; ++nf)
      b[nf] = *reinterpret_cast<const bf16x8*>(pb + brow + nf * 1024 + x1);
    __builtin_amdgcn_s_setprio(1);
#pragma unroll
    for (int fm = 0; fm < 4; ++fm)
#pragma unroll
      for (int nf = 0; nf < 4; ++nf)
        acc[fm][nf] = MFMA(a[fm], b[nf], acc[fm][nf]);
    __builtin_amdgcn_s_setprio(0);
    c ^= 1;
  }

  // epilogue: C/D layout col = lr, row = g*4 + rr
  if (tn < 4096) {
    bf16* dst = (tn < 2048) ? Qt : Kt;
    int cb = tn & 2047;
#pragma unroll
    for (int fm = 0; fm < 4; ++fm)
#pragma unroll
      for (int nf = 0; nf < 4; ++nf)
#pragma unroll
        for (int rr = 0; rr < 4; ++rr) {
          int row = tm + wr * 64 + fm * 16 + g * 4 + rr;
          int col = cb + wc * 64 + nf * 16 + lr;
          dst[(size_t)row * 2048 + col] = (bf16)acc[fm][nf][rr];
        }
  } else {
#pragma unroll
    for (int fm = 0; fm < 4; ++fm)
#pragma unroll
      for (int nf = 0; nf < 4; ++nf) {
        int row0 = tm + wr * 64 + fm * 16 + g * 4;  // 4 consecutive tokens
        int col = tn - 4096 + wc * 64 + nf * 16 + lr;
        int bb = row0 >> 11, nn = row0 & 2047;
        int hh = col >> 7, dd = col & 127;
        bf16x4 o = {(bf16)acc[fm][nf][0], (bf16)acc[fm][nf][1],
                    (bf16)acc[fm][nf][2], (bf16)acc[fm][nf][3]};
        *reinterpret_cast<bf16x4*>(
            Vt + (((size_t)bb * 16 + hh) * 128 + dd) * 2048 + nn) = o;
      }
  }
}

// ---------- bf16 GEMM, C = A * B^T (m97 structure) — output projection ----------
template <typename OutT>
__global__ __launch_bounds__(256) void k_gemm_bt(const bf16* __restrict__ A,
                                                 const bf16* __restrict__ B,
                                                 OutT* __restrict__ C,
                                                 int M, int N, int K) {
  __shared__ __align__(16) bf16 As[128 * 64];
  __shared__ __align__(16) bf16 Bs[128 * 64];
  const int tid = threadIdx.x;
  const int w = tid >> 6, l = tid & 63;
  const int lr = l & 15, g = l >> 4;
  const int tm = blockIdx.y * 128, tn = blockIdx.x * 128;
  const int wr = (w >> 1) * 64, wc = (w & 1) * 64;

  f32x4 acc[4][4] = {};

  for (int kt = 0; kt < K; kt += 64) {
#pragma unroll
    for (int r = 0; r < 4; ++r) {
      int e = r * 2048 + tid * 8;
      int row = e >> 6, col = e & 63;
      GLD(A + (size_t)(tm + row) * K + kt + col, As + r * 2048 + w * 512);
      GLD(B + (size_t)(tn + row) * K + kt + col, Bs + r * 2048 + w * 512);
    }
    __syncthreads();
#pragma unroll
    for (int kk = 0; kk < 64; kk += 32) {
      bf16x8 a[4], b[4];
#pragma unroll
      for (int i = 0; i < 4; ++i)
        a[i] = *reinterpret_cast<const bf16x8*>(As + (wr + i * 16 + lr) * 64 + kk + g * 8);
#pragma unroll
      for (int i = 0; i < 4; ++i)
        b[i] = *reinterpret_cast<const bf16x8*>(Bs + (wc + i * 16 + lr) * 64 + kk + g * 8);
#pragma unroll
      for (int i = 0; i < 4; ++i)
#pragma unroll
        for (int j = 0; j < 4; ++j)
          acc[i][j] = MFMA(a[i], b[j], acc[i][j]);
    }
    __syncthreads();
  }
#pragma unroll
  for (int i = 0; i < 4; ++i)
#pragma unroll
    for (int j = 0; j < 4; ++j)
#pragma unroll
      for (int r = 0; r < 4; ++r) {
        int row = tm + wr + i * 16 + g * 4 + r;
        int col = tn + wc + j * 16 + lr;
        C[(size_t)row * N + col] = (OutT)acc[i][j][r];
      }
}

// ---------- causal poly^4 attention ----------
// Q,K: (bh=32, 2048, 128) bf16 ; Vt: (bh, 128, 2048) bf16 ; O: (b, n, h*128) bf16
// 1-D grid of 512: flat = pair*32 + bh -> flat%8 = bh%8, so XCD k owns bh
// {k,k+8,k+16,k+24}: their K+V (4MB) fits that XCD's L2.
__global__ __launch_bounds__(256) void k_attn(const bf16* __restrict__ Q,
                                              const bf16* __restrict__ K,
                                              const bf16* __restrict__ Vt,
                                              bf16* __restrict__ O) {
  __shared__ __align__(16) bf16 Ks[128 * 128];
  __shared__ __align__(16) bf16 Vs[128 * 128];  // [hd][kv]
  __shared__ __align__(16) bf16 Ps[64 * 128];
  const int tid = threadIdx.x, w = tid >> 6, l = tid & 63;
  const int lr = l & 15, g = l >> 4;
  const int flat = blockIdx.x;
  const int pair = flat >> 5, bh = flat & 31;
  const size_t base = (size_t)bh * 2048 * 128;
  const int b_ = bh >> 4, h_ = bh & 15;

  for (int seg = 0; seg < 2; ++seg) {
    const int qt = seg ? (31 - pair) : pair;
    const int qbase = qt * 64;
    bf16x8 qf[4];
#pragma unroll
    for (int kc = 0; kc < 4; ++kc)
      qf[kc] = *reinterpret_cast<const bf16x8*>(
          Q + base + (size_t)(qbase + w * 16 + lr) * 128 + kc * 32 + g * 8);

    f32x4 on[8] = {};
    float dn[4] = {};
    const int nt = (qbase >> 7) + 1;

    for (int t = 0; t < nt; ++t) {
      const bf16* kg = K + base + (size_t)t * 128 * 128;
      const bf16* vg = Vt + base + t * 128;
#pragma unroll
      for (int r = 0; r < 8; ++r) {
        int e = r * 2048 + w * 512 + l * 8;
        int row = e >> 7, c = (e >> 3) & 15;
        int sc = ((c ^ (row & 7)) << 3);
        GLD(kg + (row << 7) + sc, Ks + r * 2048 + w * 512);
        GLD(vg + (size_t)row * 2048 + sc, Vs + r * 2048 + w * 512);
      }
      __syncthreads();

      // S = Q K^T
      f32x4 s[8] = {};
      __builtin_amdgcn_s_setprio(1);
#pragma unroll
      for (int kc = 0; kc < 4; ++kc)
#pragma unroll
        for (int ni = 0; ni < 8; ++ni) {
          bf16x8 kb = *reinterpret_cast<const bf16x8*>(
              Ks + ((ni * 16 + lr) << 7) + (((kc * 4 + g) ^ (lr & 7)) << 3));
          s[ni] = MFMA(qf[kc], kb, s[ni]);
        }
      __builtin_amdgcn_s_setprio(0);

      // mask + ^4, partial row sums, swizzled Ps writes (own-wave rows)
      float part[4] = {};
#pragma unroll
      for (int ni = 0; ni < 8; ++ni)
#pragma unroll
        for (int r = 0; r < 4; ++r) {
          int lrow = g * 4 + r;
          int qrow = qbase + w * 16 + lrow;
          int col = t * 128 + ni * 16 + lr;
          float v = s[ni][r];
          v = (col <= qrow) ? v : 0.f;
          float v2 = v * v, v4 = v2 * v2;
          part[r] += v4;
          int chunk = ni * 2 + (lr >> 3);
          Ps[((w * 16 + lrow) << 7) + ((chunk ^ (lrow & 7)) << 3) + (lr & 7)] =
              (bf16)v4;
        }
#pragma unroll
      for (int m = 1; m < 16; m <<= 1)
#pragma unroll
        for (int r = 0; r < 4; ++r) part[r] += __shfl_xor(part[r], m, 64);
#pragma unroll
      for (int r = 0; r < 4; ++r) dn[r] += part[r];

      // O += P @ V
      __builtin_amdgcn_s_setprio(1);
#pragma unroll
      for (int kc = 0; kc < 4; ++kc) {
        bf16x8 pa = *reinterpret_cast<const bf16x8*>(
            Ps + ((w * 16 + lr) << 7) + (((kc * 4 + g) ^ (lr & 7)) << 3));
#pragma unroll
        for (int ni = 0; ni < 8; ++ni) {
          bf16x8 vb = *reinterpret_cast<const bf16x8*>(
              Vs + ((ni * 16 + lr) << 7) + (((kc * 4 + g) ^ (lr & 7)) << 3));
          on[ni] = MFMA(pa, vb, on[ni]);
        }
      }
      __builtin_amdgcn_s_setprio(0);
      __syncthreads();
    }

#pragma unroll
    for (int r = 0; r < 4; ++r) {
      float inv = 1.0f / fmaxf(dn[r], 1e-6f);
      int row = qbase + w * 16 + g * 4 + r;
#pragma unroll
      for (int ni = 0; ni < 8; ++ni)
        O[((size_t)b_ * 2048 + row) * 2048 + h_ * 128 + ni * 16 + lr] =
            (bf16)(on[ni][r] * inv);
    }
  }
}

extern "C" void kernel_launch(void* const* d_in, const int* in_sizes, int n_in,
                              void* d_out, int out_size, void* d_ws, size_t ws_size,
                              hipStream_t stream) {
  const float* x  = (const float*)d_in[0];
  const float* Wq = (const float*)d_in[1];
  const float* Wk = (const float*)d_in[2];
  const float* Wv = (const float*)d_in[3];
  const float* Wo = (const float*)d_in[4];
  float* out = (float*)d_out;

  char* p = (char*)d_ws;
  bf16* xb   = (bf16*)p; p += (size_t)8388608 * 2;    // x bf16 (4096x2048)
  bf16* wqkv = (bf16*)p; p += (size_t)12582912 * 2;   // [Wq;Wk;Wv] (6144x2048)
  bf16* wob  = (bf16*)p; p += (size_t)4194304 * 2;    // Wo bf16
  bf16* Qtmp = (bf16*)p; p += (size_t)8388608 * 2;    // Q pre-rope (b,n,h,hd)
  bf16* Ktmp = (bf16*)p; p += (size_t)8388608 * 2;    // K pre-rope
  bf16* Vt   = (bf16*)p; p += (size_t)8388608 * 2;    // (b,h,128,n)
  bf16* Qp   = (bf16*)p; p += (size_t)8388608 * 2;    // (b,h,n,128)
  bf16* Kp   = (bf16*)p; p += (size_t)8388608 * 2;    // (b,h,n,128)
  float* ct  = (float*)p; p += (size_t)131072 * 4;
  float* st  = (float*)p; p += (size_t)131072 * 4;
  bf16* Ob = Qtmp;  // attn out aliases Qtmp (dead after rope)

  k_cvt<<<8192, 256, 0, stream>>>(x, xb, 2097152);
  k_cvt3<<<12288, 256, 0, stream>>>(Wq, Wk, Wv, wqkv);
  k_cvt<<<4096, 256, 0, stream>>>(Wo, wob, 1048576);
  k_rope_tab<<<512, 256, 0, stream>>>(ct, st);

  k_gemm_qkv<<<dim3(48, 16), 512, 0, stream>>>(xb, wqkv, Qtmp, Ktmp, Vt);
  k_rope<<<16384, 256, 0, stream>>>(Qtmp, Qp, ct, st);
  k_rope<<<16384, 256, 0, stream>>>(Ktmp, Kp, ct, st);

  k_attn<<<512, 256, 0, stream>>>(Qp, Kp, Vt, Ob);

  dim3 gg(16, 32);
  k_gemm_bt<float><<<gg, 256, 0, stream>>>(Ob, wob, out, 4096, 2048, 2048);
}

// Round 4
// 270.336 us; speedup vs baseline: 1.7811x; 1.1026x over previous
//
#include <hip/hip_runtime.h>

// PolyAttention on MI355X (gfx950).
// cvt f32->bf16 -> fused QKV GEMM (256x128, BK=32, triple-buffer LDS, counted
// vmcnt pipeline, rope fused in epilogue, V transposed) -> causal poly(^4)
// attention -> output GEMM (same pipeline).  b=2, n=2048, d=2048, h=16, hd=128.

typedef __bf16 bf16;
typedef __bf16 bf16x8 __attribute__((ext_vector_type(8)));
typedef __bf16 bf16x4 __attribute__((ext_vector_type(4)));
typedef float f32x4 __attribute__((ext_vector_type(4)));

#define GLD(g, l)                                                   \
  __builtin_amdgcn_global_load_lds(                                 \
      (const __attribute__((address_space(1))) void*)(g),           \
      (__attribute__((address_space(3))) void*)(l), 16, 0, 0)

#define MFMA(a, b, c) __builtin_amdgcn_mfma_f32_16x16x32_bf16(a, b, c, 0, 0, 0)

// ---------- f32 -> bf16 conversion, 4 elems/thread ----------
__global__ __launch_bounds__(256) void k_cvt(const float* __restrict__ in,
                                             bf16* __restrict__ out, int n4) {
  int i = blockIdx.x * 256 + threadIdx.x;
  if (i >= n4) return;
  float4 v = reinterpret_cast<const float4*>(in)[i];
  bf16x4 o = {(bf16)v.x, (bf16)v.y, (bf16)v.z, (bf16)v.w};
  reinterpret_cast<bf16x4*>(out)[i] = o;
}

// ---------- 3x weight cvt into concatenated wqkv (6144 x 2048) ----------
__global__ __launch_bounds__(256) void k_cvt3(const float* __restrict__ a,
                                              const float* __restrict__ b,
                                              const float* __restrict__ c,
                                              bf16* __restrict__ out) {
  int i = blockIdx.x * 256 + threadIdx.x;
  const float* src = (i < 1048576) ? a : ((i < 2097152) ? b : c);
  int off = i & 1048575;
  float4 v = reinterpret_cast<const float4*>(src)[off];
  bf16x4 o = {(bf16)v.x, (bf16)v.y, (bf16)v.z, (bf16)v.w};
  reinterpret_cast<bf16x4*>(out)[i] = o;
}

// ---------- RoPE cos/sin table: (n=2048, half=64) ----------
__global__ __launch_bounds__(256) void k_rope_tab(float* __restrict__ ct,
                                                  float* __restrict__ st) {
  int i = blockIdx.x * 256 + threadIdx.x;
  if (i >= 2048 * 64) return;
  int pos = i >> 6, f = i & 63;
  float theta = exp2f(-(float)f * 0.20762050593046014f);  // 10000^(-f/64)
  float ang = (float)pos * theta;
  ct[i] = cosf(ang);
  st[i] = sinf(ang);
}

// ---------- fused QKV GEMM + rope epilogue ----------
// C = A * B^T, A: 4096x2048 (xb), B: 6144x2048 (wqkv). BM=256, BN=128, BK=32.
// 4 waves (2M x 2N), per-wave 128x64 (8x4 frags). Triple-buffered LDS (72KB,
// 2 blocks/CU). Schedule per K-tile: vmcnt(6) gate -> s_barrier -> stage(t+2)
// -> 12 ds_read_b128 -> 32 MFMA. Loads span 2 iterations, queue never drains.
// Epilogue: Q/K tiles -> LDS exchange + rope -> (b,h,n,128); V -> transposed.
__global__ __launch_bounds__(256, 2) void k_gemm_qkv(
    const bf16* __restrict__ Am, const bf16* __restrict__ Bm,
    bf16* __restrict__ Qp, bf16* __restrict__ Kp, bf16* __restrict__ Vt,
    const float* __restrict__ ct, const float* __restrict__ st) {
  __shared__ __align__(16) char LDS[73728];  // 3 x (16KB A + 8KB B)
  const int tid = threadIdx.x, w = tid >> 6, l = tid & 63;
  const int lr = l & 15, g = l >> 4;
  const int wr = w >> 1, wc = w & 1;
  const int tm = blockIdx.y * 256, tn = blockIdx.x * 128;

  // staging swizzle: row rl = tid>>2, chunk (tid&3) ^ (rl&3) ^ ((rl>>2)&3)
  const int rl = tid >> 2;
  const int scol = (((tid & 3) ^ (rl & 3) ^ ((rl >> 2) & 3)) << 3);
  // ds-read swizzled chunk offset (bytes): (g ^ (lr&3) ^ ((lr>>2)&3)) * 16
  const int xo = ((g ^ (lr & 3) ^ ((lr >> 2) & 3)) << 4);

#define STAGEQ(buf, kt)                                                      \
  {                                                                          \
    _Pragma("unroll") for (int i = 0; i < 4; ++i)                            \
        GLD(Am + (size_t)(tm + i * 64 + rl) * 2048 + (kt) + scol,            \
            LDS + (buf) * 24576 + i * 4096 + tid * 16);                      \
    _Pragma("unroll") for (int i = 0; i < 2; ++i)                            \
        GLD(Bm + (size_t)(tn + i * 64 + rl) * 2048 + (kt) + scol,            \
            LDS + (buf) * 24576 + 16384 + i * 4096 + tid * 16);              \
  }

  f32x4 acc[8][4] = {};

  STAGEQ(0, 0);
  STAGEQ(1, 32);
  int cur = 0, st3 = 2;
  for (int t = 0; t < 63; ++t) {
    asm volatile("s_waitcnt vmcnt(6)" ::: "memory");  // own tile-t landed
    __builtin_amdgcn_s_barrier();                     // everyone's landed
    asm volatile("" ::: "memory");
    if (t < 62) STAGEQ(st3, (t + 2) * 32);
    const char* pa = LDS + cur * 24576;
    const char* pb = pa + 16384;
    bf16x8 a[8], b[4];
#pragma unroll
    for (int fm = 0; fm < 8; ++fm)
      a[fm] = *reinterpret_cast<const bf16x8*>(pa + (wr * 128 + fm * 16 + lr) * 64 + xo);
#pragma unroll
    for (int nf = 0; nf < 4; ++nf)
      b[nf] = *reinterpret_cast<const bf16x8*>(pb + (wc * 64 + nf * 16 + lr) * 64 + xo);
    __builtin_amdgcn_s_setprio(1);
#pragma unroll
    for (int fm = 0; fm < 8; ++fm)
#pragma unroll
      for (int nf = 0; nf < 4; ++nf)
        acc[fm][nf] = MFMA(a[fm], b[nf], acc[fm][nf]);
    __builtin_amdgcn_s_setprio(0);
    cur = (cur == 2) ? 0 : cur + 1;
    st3 = (st3 == 2) ? 0 : st3 + 1;
  }
  {  // peeled last tile: must fully drain own loads
    asm volatile("s_waitcnt vmcnt(0)" ::: "memory");
    __builtin_amdgcn_s_barrier();
    asm volatile("" ::: "memory");
    const char* pa = LDS + cur * 24576;
    const char* pb = pa + 16384;
    bf16x8 a[8], b[4];
#pragma unroll
    for (int fm = 0; fm < 8; ++fm)
      a[fm] = *reinterpret_cast<const bf16x8*>(pa + (wr * 128 + fm * 16 + lr) * 64 + xo);
#pragma unroll
    for (int nf = 0; nf < 4; ++nf)
      b[nf] = *reinterpret_cast<const bf16x8*>(pb + (wc * 64 + nf * 16 + lr) * 64 + xo);
#pragma unroll
    for (int fm = 0; fm < 8; ++fm)
#pragma unroll
      for (int nf = 0; nf < 4; ++nf)
        acc[fm][nf] = MFMA(a[fm], b[nf], acc[fm][nf]);
  }

  if (tn < 4096) {
    // Q or K tile (one head): exchange halves via LDS, apply rope, store.
    __syncthreads();  // all waves done reading staging LDS
    bf16* E = (bf16*)LDS;  // [256][136] padded
#pragma unroll
    for (int fm = 0; fm < 8; ++fm)
#pragma unroll
      for (int nf = 0; nf < 4; ++nf)
#pragma unroll
        for (int rr = 0; rr < 4; ++rr)
          E[(wr * 128 + fm * 16 + g * 4 + rr) * 136 + wc * 64 + nf * 16 + lr] =
              (bf16)acc[fm][nf][rr];
    __syncthreads();
    const int hh = (tn & 2047) >> 7;
    bf16* dst = (tn < 2048) ? Qp : Kp;
#pragma unroll
    for (int i = 0; i < 16; ++i) {
      int task = i * 256 + tid;
      int row = task >> 4, dg = (task & 15) << 2;
      int token = tm + row, nn = token & 2047, bb = token >> 11;
      f32x4 c4 = *reinterpret_cast<const f32x4*>(ct + nn * 64 + dg);
      f32x4 s4 = *reinterpret_cast<const f32x4*>(st + nn * 64 + dg);
      bf16x4 x1 = *reinterpret_cast<const bf16x4*>(E + row * 136 + dg);
      bf16x4 x2 = *reinterpret_cast<const bf16x4*>(E + row * 136 + 64 + dg);
      bf16x4 o1, o2;
#pragma unroll
      for (int j = 0; j < 4; ++j) {
        float a1 = (float)x1[j], a2 = (float)x2[j];
        o1[j] = (bf16)(a1 * c4[j] - a2 * s4[j]);
        o2[j] = (bf16)(a1 * s4[j] + a2 * c4[j]);
      }
      size_t rb = (((size_t)bb * 16 + hh) * 2048 + nn) * 128;
      *reinterpret_cast<bf16x4*>(dst + rb + dg) = o1;
      *reinterpret_cast<bf16x4*>(dst + rb + 64 + dg) = o2;
    }
  } else {
    // V tile: transposed store (b,h,128,n); 4 consecutive tokens per bf16x4
#pragma unroll
    for (int fm = 0; fm < 8; ++fm)
#pragma unroll
      for (int nf = 0; nf < 4; ++nf) {
        int row0 = tm + wr * 128 + fm * 16 + g * 4;
        int col = (tn - 4096) + wc * 64 + nf * 16 + lr;
        int bb = row0 >> 11, nn = row0 & 2047;
        int hh = col >> 7, dd = col & 127;
        bf16x4 o = {(bf16)acc[fm][nf][0], (bf16)acc[fm][nf][1],
                    (bf16)acc[fm][nf][2], (bf16)acc[fm][nf][3]};
        *reinterpret_cast<bf16x4*>(
            Vt + (((size_t)bb * 16 + hh) * 128 + dd) * 2048 + nn) = o;
      }
  }
}

// ---------- output GEMM: C(f32) = A * B^T, 4096x2048x2048 ----------
// BM=BN=128, BK=32, 4 waves (2x2), per-wave 64x64. Triple-buffer (48KB,
// 3 blocks/CU), same counted-vmcnt schedule with gate vmcnt(4).
__global__ __launch_bounds__(256, 3) void k_gemm_out(const bf16* __restrict__ Am,
                                                     const bf16* __restrict__ Bm,
                                                     float* __restrict__ C) {
  __shared__ __align__(16) char LDS[49152];  // 3 x (8KB A + 8KB B)
  const int tid = threadIdx.x, w = tid >> 6, l = tid & 63;
  const int lr = l & 15, g = l >> 4;
  const int wr = w >> 1, wc = w & 1;
  const int tm = blockIdx.y * 128, tn = blockIdx.x * 128;

  const int rl = tid >> 2;
  const int scol = (((tid & 3) ^ (rl & 3) ^ ((rl >> 2) & 3)) << 3);
  const int xo = ((g ^ (lr & 3) ^ ((lr >> 2) & 3)) << 4);

#define STAGEO(buf, kt)                                                      \
  {                                                                          \
    _Pragma("unroll") for (int i = 0; i < 2; ++i)                            \
        GLD(Am + (size_t)(tm + i * 64 + rl) * 2048 + (kt) + scol,            \
            LDS + (buf) * 16384 + i * 4096 + tid * 16);                      \
    _Pragma("unroll") for (int i = 0; i < 2; ++i)                            \
        GLD(Bm + (size_t)(tn + i * 64 + rl) * 2048 + (kt) + scol,            \
            LDS + (buf) * 16384 + 8192 + i * 4096 + tid * 16);               \
  }

  f32x4 acc[4][4] = {};

  STAGEO(0, 0);
  STAGEO(1, 32);
  int cur = 0, st3 = 2;
  for (int t = 0; t < 63; ++t) {
    asm volatile("s_waitcnt vmcnt(4)" ::: "memory");
    __builtin_amdgcn_s_barrier();
    asm volatile("" ::: "memory");
    if (t < 62) STAGEO(st3, (t + 2) * 32);
    const char* pa = LDS + cur * 16384;
    const char* pb = pa + 8192;
    bf16x8 a[4], b[4];
#pragma unroll
    for (int fm = 0; fm < 4; ++fm)
      a[fm] = *reinterpret_cast<const bf16x8*>(pa + (wr * 64 + fm * 16 + lr) * 64 + xo);
#pragma unroll
    for (int nf = 0; nf < 4; ++nf)
      b[nf] = *reinterpret_cast<const bf16x8*>(pb + (wc * 64 + nf * 16 + lr) * 64 + xo);
    __builtin_amdgcn_s_setprio(1);
#pragma unroll
    for (int fm = 0; fm < 4; ++fm)
#pragma unroll
      for (int nf = 0; nf < 4; ++nf)
        acc[fm][nf] = MFMA(a[fm], b[nf], acc[fm][nf]);
    __builtin_amdgcn_s_setprio(0);
    cur = (cur == 2) ? 0 : cur + 1;
    st3 = (st3 == 2) ? 0 : st3 + 1;
  }
  {
    asm volatile("s_waitcnt vmcnt(0)" ::: "memory");
    __builtin_amdgcn_s_barrier();
    asm volatile("" ::: "memory");
    const char* pa = LDS + cur * 16384;
    const char* pb = pa + 8192;
    bf16x8 a[4], b[4];
#pragma unroll
    for (int fm = 0; fm < 4; ++fm)
      a[fm] = *reinterpret_cast<const bf16x8*>(pa + (wr * 64 + fm * 16 + lr) * 64 + xo);
#pragma unroll
    for (int nf = 0; nf < 4; ++nf)
      b[nf] = *reinterpret_cast<const bf16x8*>(pb + (wc * 64 + nf * 16 + lr) * 64 + xo);
#pragma unroll
    for (int fm = 0; fm < 4; ++fm)
#pragma unroll
      for (int nf = 0; nf < 4; ++nf)
        acc[fm][nf] = MFMA(a[fm], b[nf], acc[fm][nf]);
  }

#pragma unroll
  for (int fm = 0; fm < 4; ++fm)
#pragma unroll
    for (int nf = 0; nf < 4; ++nf)
#pragma unroll
      for (int rr = 0; rr < 4; ++rr) {
        int row = tm + wr * 64 + fm * 16 + g * 4 + rr;
        int col = tn + wc * 64 + nf * 16 + lr;
        C[(size_t)row * 2048 + col] = acc[fm][nf][rr];
      }
}

// ---------- causal poly^4 attention (unchanged from round 3) ----------
__global__ __launch_bounds__(256) void k_attn(const bf16* __restrict__ Q,
                                              const bf16* __restrict__ K,
                                              const bf16* __restrict__ Vt,
                                              bf16* __restrict__ O) {
  __shared__ __align__(16) bf16 Ks[128 * 128];
  __shared__ __align__(16) bf16 Vs[128 * 128];  // [hd][kv]
  __shared__ __align__(16) bf16 Ps[64 * 128];
  const int tid = threadIdx.x, w = tid >> 6, l = tid & 63;
  const int lr = l & 15, g = l >> 4;
  const int flat = blockIdx.x;
  const int pair = flat >> 5, bh = flat & 31;
  const size_t base = (size_t)bh * 2048 * 128;
  const int b_ = bh >> 4, h_ = bh & 15;

  for (int seg = 0; seg < 2; ++seg) {
    const int qt = seg ? (31 - pair) : pair;
    const int qbase = qt * 64;
    bf16x8 qf[4];
#pragma unroll
    for (int kc = 0; kc < 4; ++kc)
      qf[kc] = *reinterpret_cast<const bf16x8*>(
          Q + base + (size_t)(qbase + w * 16 + lr) * 128 + kc * 32 + g * 8);

    f32x4 on[8] = {};
    float dn[4] = {};
    const int nt = (qbase >> 7) + 1;

    for (int t = 0; t < nt; ++t) {
      const bf16* kg = K + base + (size_t)t * 128 * 128;
      const bf16* vg = Vt + base + t * 128;
#pragma unroll
      for (int r = 0; r < 8; ++r) {
        int e = r * 2048 + w * 512 + l * 8;
        int row = e >> 7, c = (e >> 3) & 15;
        int sc = ((c ^ (row & 7)) << 3);
        GLD(kg + (row << 7) + sc, Ks + r * 2048 + w * 512);
        GLD(vg + (size_t)row * 2048 + sc, Vs + r * 2048 + w * 512);
      }
      __syncthreads();

      f32x4 s[8] = {};
      __builtin_amdgcn_s_setprio(1);
#pragma unroll
      for (int kc = 0; kc < 4; ++kc)
#pragma unroll
        for (int ni = 0; ni < 8; ++ni) {
          bf16x8 kb = *reinterpret_cast<const bf16x8*>(
              Ks + ((ni * 16 + lr) << 7) + (((kc * 4 + g) ^ (lr & 7)) << 3));
          s[ni] = MFMA(qf[kc], kb, s[ni]);
        }
      __builtin_amdgcn_s_setprio(0);

      float part[4] = {};
#pragma unroll
      for (int ni = 0; ni < 8; ++ni)
#pragma unroll
        for (int r = 0; r < 4; ++r) {
          int lrow = g * 4 + r;
          int qrow = qbase + w * 16 + lrow;
          int col = t * 128 + ni * 16 + lr;
          float v = s[ni][r];
          v = (col <= qrow) ? v : 0.f;
          float v2 = v * v, v4 = v2 * v2;
          part[r] += v4;
          int chunk = ni * 2 + (lr >> 3);
          Ps[((w * 16 + lrow) << 7) + ((chunk ^ (lrow & 7)) << 3) + (lr & 7)] =
              (bf16)v4;
        }
#pragma unroll
      for (int m = 1; m < 16; m <<= 1)
#pragma unroll
        for (int r = 0; r < 4; ++r) part[r] += __shfl_xor(part[r], m, 64);
#pragma unroll
      for (int r = 0; r < 4; ++r) dn[r] += part[r];

      __builtin_amdgcn_s_setprio(1);
#pragma unroll
      for (int kc = 0; kc < 4; ++kc) {
        bf16x8 pa = *reinterpret_cast<const bf16x8*>(
            Ps + ((w * 16 + lr) << 7) + (((kc * 4 + g) ^ (lr & 7)) << 3));
#pragma unroll
        for (int ni = 0; ni < 8; ++ni) {
          bf16x8 vb = *reinterpret_cast<const bf16x8*>(
              Vs + ((ni * 16 + lr) << 7) + (((kc * 4 + g) ^ (lr & 7)) << 3));
          on[ni] = MFMA(pa, vb, on[ni]);
        }
      }
      __builtin_amdgcn_s_setprio(0);
      __syncthreads();
    }

#pragma unroll
    for (int r = 0; r < 4; ++r) {
      float inv = 1.0f / fmaxf(dn[r], 1e-6f);
      int row = qbase + w * 16 + g * 4 + r;
#pragma unroll
      for (int ni = 0; ni < 8; ++ni)
        O[((size_t)b_ * 2048 + row) * 2048 + h_ * 128 + ni * 16 + lr] =
            (bf16)(on[ni][r] * inv);
    }
  }
}

extern "C" void kernel_launch(void* const* d_in, const int* in_sizes, int n_in,
                              void* d_out, int out_size, void* d_ws, size_t ws_size,
                              hipStream_t stream) {
  const float* x  = (const float*)d_in[0];
  const float* Wq = (const float*)d_in[1];
  const float* Wk = (const float*)d_in[2];
  const float* Wv = (const float*)d_in[3];
  const float* Wo = (const float*)d_in[4];
  float* out = (float*)d_out;

  char* p = (char*)d_ws;
  bf16* xb   = (bf16*)p; p += (size_t)8388608 * 2;    // x bf16 (4096x2048)
  bf16* wqkv = (bf16*)p; p += (size_t)12582912 * 2;   // [Wq;Wk;Wv] (6144x2048)
  bf16* wob  = (bf16*)p; p += (size_t)4194304 * 2;    // Wo bf16
  bf16* Qp   = (bf16*)p; p += (size_t)8388608 * 2;    // roped (b,h,n,128)
  bf16* Kp   = (bf16*)p; p += (size_t)8388608 * 2;    // roped (b,h,n,128)
  bf16* Vt   = (bf16*)p; p += (size_t)8388608 * 2;    // (b,h,128,n)
  bf16* Ob   = (bf16*)p; p += (size_t)8388608 * 2;    // attn out (b,n,h*128)
  float* ct  = (float*)p; p += (size_t)131072 * 4;
  float* st  = (float*)p; p += (size_t)131072 * 4;

  k_cvt<<<8192, 256, 0, stream>>>(x, xb, 2097152);
  k_cvt3<<<12288, 256, 0, stream>>>(Wq, Wk, Wv, wqkv);
  k_cvt<<<4096, 256, 0, stream>>>(Wo, wob, 1048576);
  k_rope_tab<<<512, 256, 0, stream>>>(ct, st);

  k_gemm_qkv<<<dim3(48, 16), 256, 0, stream>>>(xb, wqkv, Qp, Kp, Vt, ct, st);

  k_attn<<<512, 256, 0, stream>>>(Qp, Kp, Vt, Ob);

  k_gemm_out<<<dim3(16, 32), 256, 0, stream>>>(Ob, wob, out);
}